// Round 2
// baseline (697.988 us; speedup 1.0000x reference)
//
#include <hip/hip_runtime.h>
#include <math.h>

#define BB 256
#define SS 4096
#define HH 128
#define SPLIT 8
#define SCHUNK (SS / SPLIT)   // 512 rows per block
#define NW 4                  // waves per block
#define NTHREADS (NW * 64)

__device__ __forceinline__ float fast_tanh(float x) {
    // tanh(x) = 1 - 2/(1+exp(2x)); overflow -> inf -> 1, underflow -> 0 -> -1 (both correct)
    return 1.0f - 2.0f / (1.0f + __expf(2.0f * x));
}

__global__ __launch_bounds__(NTHREADS) void attn_pass1(
    const float* __restrict__ x, const float* __restrict__ w,
    float* __restrict__ pm, float* __restrict__ pl, float* __restrict__ pc)
{
    const int b     = blockIdx.x / SPLIT;
    const int chunk = blockIdx.x % SPLIT;
    const int wave  = threadIdx.x >> 6;
    const int lane  = threadIdx.x & 63;

    // float2 view: lane i owns h = 2i, 2i+1. One wave reads a full 512B row, coalesced.
    const float2* __restrict__ x2 =
        (const float2*)x + (size_t)b * (SS * (HH / 2)) + (size_t)(chunk * SCHUNK) * (HH / 2);
    const float2 wv = ((const float2*)w)[lane];

    // per-wave online softmax state
    float m = -INFINITY, l = 0.f, c0 = 0.f, c1 = 0.f;

    for (int s = wave; s < SCHUNK; s += NW) {
        float2 v = x2[(size_t)s * (HH / 2) + lane];
        float t = fast_tanh(v.x) * wv.x + fast_tanh(v.y) * wv.y;
        // full-wave (64-lane) all-reduce sum -> score for this row
        #pragma unroll
        for (int off = 1; off < 64; off <<= 1)
            t += __shfl_xor(t, off, 64);
        float nm = fmaxf(m, t);
        float sc = __expf(m - nm);   // first iter: exp(-inf) = 0, correct
        float p  = __expf(t - nm);
        l  = l  * sc + p;
        c0 = c0 * sc + p * v.x;
        c1 = c1 * sc + p * v.y;
        m  = nm;
    }

    // combine the NW wave-partials in LDS
    __shared__ float sm[NW], sl[NW], scx[NW][HH];
    if (lane == 0) { sm[wave] = m; sl[wave] = l; }
    scx[wave][2 * lane]     = c0;
    scx[wave][2 * lane + 1] = c1;
    __syncthreads();

    if (wave == 0) {
        float M = sm[0];
        #pragma unroll
        for (int i = 1; i < NW; i++) M = fmaxf(M, sm[i]);
        float L = 0.f, C0 = 0.f, C1 = 0.f;
        #pragma unroll
        for (int i = 0; i < NW; i++) {
            float e = __expf(sm[i] - M);
            L  += sl[i] * e;
            C0 += scx[i][2 * lane]     * e;
            C1 += scx[i][2 * lane + 1] * e;
        }
        const int idx = b * SPLIT + chunk;
        if (lane == 0) { pm[idx] = M; pl[idx] = L; }
        pc[(size_t)idx * HH + 2 * lane]     = C0;
        pc[(size_t)idx * HH + 2 * lane + 1] = C1;
    }
}

__global__ __launch_bounds__(64) void attn_pass2(
    const float* __restrict__ pm, const float* __restrict__ pl,
    const float* __restrict__ pc, float* __restrict__ out)
{
    const int b    = blockIdx.x;
    const int lane = threadIdx.x;  // 64 threads, lane owns h = 2*lane, 2*lane+1

    float M = -INFINITY;
    #pragma unroll
    for (int i = 0; i < SPLIT; i++) M = fmaxf(M, pm[b * SPLIT + i]);

    float L = 0.f, C0 = 0.f, C1 = 0.f;
    #pragma unroll
    for (int i = 0; i < SPLIT; i++) {
        float e = __expf(pm[b * SPLIT + i] - M);
        L  += pl[b * SPLIT + i] * e;
        C0 += pc[(size_t)(b * SPLIT + i) * HH + 2 * lane]     * e;
        C1 += pc[(size_t)(b * SPLIT + i) * HH + 2 * lane + 1] * e;
    }
    out[b * HH + 2 * lane]     = C0 / L;
    out[b * HH + 2 * lane + 1] = C1 / L;
}

extern "C" void kernel_launch(void* const* d_in, const int* in_sizes, int n_in,
                              void* d_out, int out_size, void* d_ws, size_t ws_size,
                              hipStream_t stream) {
    const float* x = (const float*)d_in[0];   // [B, S, H] fp32
    const float* w = (const float*)d_in[1];   // [H, 1]    fp32
    float* out = (float*)d_out;               // [B, H]    fp32

    // workspace layout: pm[B*SPLIT] | pl[B*SPLIT] | pc[B*SPLIT*H]
    float* pm = (float*)d_ws;
    float* pl = pm + BB * SPLIT;
    float* pc = pl + BB * SPLIT;

    attn_pass1<<<BB * SPLIT, NTHREADS, 0, stream>>>(x, w, pm, pl, pc);
    attn_pass2<<<BB, 64, 0, stream>>>(pm, pl, pc, out);
}

// Round 3
// 682.161 us; speedup vs baseline: 1.0232x; 1.0232x over previous
//
#include <hip/hip_runtime.h>
#include <math.h>

#define BB 256
#define SS 4096
#define HH 128
#define SPLIT 8
#define SCHUNK (SS / SPLIT)   // 512 rows per block
#define NW 4                  // waves per block
#define NTHREADS (NW * 64)

__device__ __forceinline__ float fast_tanh(float x) {
    // tanh(x) = 1 - 2/(1+exp(2x)); overflow -> inf -> 1, underflow -> 0 -> -1 (both correct)
    return 1.0f - 2.0f / (1.0f + __expf(2.0f * x));
}

__global__ __launch_bounds__(NTHREADS) void attn_pass1(
    const float* __restrict__ x, const float* __restrict__ w,
    float* __restrict__ pm, float* __restrict__ pl, float* __restrict__ pc)
{
    const int b     = blockIdx.x / SPLIT;
    const int chunk = blockIdx.x % SPLIT;
    const int wave  = threadIdx.x >> 6;
    const int lane  = threadIdx.x & 63;
    const int half  = lane >> 5;   // 0: even row of pair, 1: odd row
    const int hl    = lane & 31;   // lane within half; owns h = 4*hl .. 4*hl+3

    // float4 view: one wave iteration reads TWO rows (1024B) fully coalesced.
    const float4* __restrict__ x4 =
        (const float4*)x + (size_t)b * (SS * (HH / 4)) + (size_t)(chunk * SCHUNK) * (HH / 4);
    const float4 wv = ((const float4*)w)[hl];

    // per-half-wave online softmax state (each half covers all 128 h for its row subset)
    float m = -INFINITY, l = 0.f, c0 = 0.f, c1 = 0.f, c2 = 0.f, c3 = 0.f;

    #pragma unroll 2
    for (int p = wave; p < SCHUNK / 2; p += NW) {
        // row = 2p + half, float4 col = hl  ->  flat index p*64 + lane
        float4 v = x4[(size_t)p * 64 + lane];
        float t = fast_tanh(v.x) * wv.x + fast_tanh(v.y) * wv.y
                + fast_tanh(v.z) * wv.z + fast_tanh(v.w) * wv.w;
        // 32-lane all-reduce within each half (offsets 1..16 never cross halves)
        #pragma unroll
        for (int off = 1; off < 32; off <<= 1)
            t += __shfl_xor(t, off, 64);
        // defer-max: rescale only when the max actually grows (uniform per half)
        if (t > m) {
            float sc = __expf(m - t);   // first iter: exp(-inf)=0, state is 0 anyway
            l *= sc; c0 *= sc; c1 *= sc; c2 *= sc; c3 *= sc;
            m = t;
        }
        float pp = __expf(t - m);
        l  += pp;
        c0 += pp * v.x; c1 += pp * v.y; c2 += pp * v.z; c3 += pp * v.w;
    }

    // combine the NW*2 half-wave partials in LDS
    __shared__ float sm[NW * 2], sl[NW * 2], scx[NW * 2][HH];
    const int part = wave * 2 + half;
    if (hl == 0) { sm[part] = m; sl[part] = l; }
    scx[part][4 * hl + 0] = c0;
    scx[part][4 * hl + 1] = c1;
    scx[part][4 * hl + 2] = c2;
    scx[part][4 * hl + 3] = c3;
    __syncthreads();

    if (wave == 0) {
        float M = sm[0];
        #pragma unroll
        for (int i = 1; i < NW * 2; i++) M = fmaxf(M, sm[i]);
        float L = 0.f, C0 = 0.f, C1 = 0.f;
        #pragma unroll
        for (int i = 0; i < NW * 2; i++) {
            float e = __expf(sm[i] - M);
            L  += sl[i] * e;
            C0 += scx[i][2 * lane]     * e;
            C1 += scx[i][2 * lane + 1] * e;
        }
        const int idx = b * SPLIT + chunk;
        if (lane == 0) { pm[idx] = M; pl[idx] = L; }
        pc[(size_t)idx * HH + 2 * lane]     = C0;
        pc[(size_t)idx * HH + 2 * lane + 1] = C1;
    }
}

__global__ __launch_bounds__(64) void attn_pass2(
    const float* __restrict__ pm, const float* __restrict__ pl,
    const float* __restrict__ pc, float* __restrict__ out)
{
    const int b    = blockIdx.x;
    const int lane = threadIdx.x;  // 64 threads, lane owns h = 2*lane, 2*lane+1

    float M = -INFINITY;
    #pragma unroll
    for (int i = 0; i < SPLIT; i++) M = fmaxf(M, pm[b * SPLIT + i]);

    float L = 0.f, C0 = 0.f, C1 = 0.f;
    #pragma unroll
    for (int i = 0; i < SPLIT; i++) {
        float e = __expf(pm[b * SPLIT + i] - M);
        L  += pl[b * SPLIT + i] * e;
        C0 += pc[(size_t)(b * SPLIT + i) * HH + 2 * lane]     * e;
        C1 += pc[(size_t)(b * SPLIT + i) * HH + 2 * lane + 1] * e;
    }
    out[b * HH + 2 * lane]     = C0 / L;
    out[b * HH + 2 * lane + 1] = C1 / L;
}

extern "C" void kernel_launch(void* const* d_in, const int* in_sizes, int n_in,
                              void* d_out, int out_size, void* d_ws, size_t ws_size,
                              hipStream_t stream) {
    const float* x = (const float*)d_in[0];   // [B, S, H] fp32
    const float* w = (const float*)d_in[1];   // [H, 1]    fp32
    float* out = (float*)d_out;               // [B, H]    fp32

    // workspace layout: pm[B*SPLIT] | pl[B*SPLIT] | pc[B*SPLIT*H]
    float* pm = (float*)d_ws;
    float* pl = pm + BB * SPLIT;
    float* pc = pl + BB * SPLIT;

    attn_pass1<<<BB * SPLIT, NTHREADS, 0, stream>>>(x, w, pm, pl, pc);
    attn_pass2<<<BB, 64, 0, stream>>>(pm, pl, pc, out);
}